// Round 1
// baseline (359.381 us; speedup 1.0000x reference)
//
#include <hip/hip_runtime.h>
#include <math.h>

#define B 16
#define Q 300
#define T 50
#define NC 80
#define CL 81
#define HH 128
#define WW 128

// ws layout: int tc[B*Q]; float acc[8]
// acc: 0 ce_num, 1 ce_den, 2 bbox_sum, 3 giou_sum, 4 focal_sum, 5 boxl_sum, 6 num_pos

__global__ void init_kernel(int* tc, float* acc) {
    int i = blockIdx.x * blockDim.x + threadIdx.x;
    if (i < B * Q) tc[i] = NC;
    if (i < 8) acc[i] = 0.f;
}

__device__ __forceinline__ void boxn_calc(const float* tgt_boxes, int b, int tt,
                                          float w_im, float h_im, float* o) {
    const float* tb = tgt_boxes + (b * T + tt) * 4;
    float x1 = tb[0] / w_im, y1 = tb[1] / h_im, x2 = tb[2] / w_im, y2 = tb[3] / h_im;
    o[0] = (x1 + x2) * 0.5f; o[1] = (y1 + y2) * 0.5f; o[2] = x2 - x1; o[3] = y2 - y1;
}

__global__ void pairs_kernel(const float* pred_boxes, const float* heatmap,
                             const float* box_map, const float* tgt_boxes,
                             const int* tgt_labels, const float* tgt_sizes,
                             const int* src_idx, const int* tgt_idx,
                             int* tc, float* acc) {
    int i = blockIdx.x * blockDim.x + threadIdx.x;
    if (i >= B * T) return;
    int b = i / T, t = i % T;
    float h_im = tgt_sizes[b * 2 + 0], w_im = tgt_sizes[b * 2 + 1];

    float bf[4];
    boxn_calc(tgt_boxes, b, t, w_im, h_im, bf);
    int gx = min(max((int)(bf[0] * WW), 0), WW - 1);
    int gy = min(max((int)(bf[1] * HH), 0), HH - 1);
    int lf = tgt_labels[b * T + t];

    // scatter target class: target_classes[b, src_idx[b,t]] = tgt_labels[b, tgt_idx[b,t]]
    int ti = tgt_idx[b * T + t];
    tc[b * Q + src_idx[b * T + t]] = tgt_labels[b * T + ti];

    // dedupe among targets in same batch mapping to same cell
    bool first_cell = true, first_hm = true, last_cell = true;
    for (int tt = 0; tt < T; ++tt) {
        if (tt == t) continue;
        float o[4];
        boxn_calc(tgt_boxes, b, tt, w_im, h_im, o);
        int ox = min(max((int)(o[0] * WW), 0), WW - 1);
        int oy = min(max((int)(o[1] * HH), 0), HH - 1);
        if (ox == gx && oy == gy) {
            if (tt < t) first_cell = false;
            if (tt > t) last_cell = false;
            if (tt < t && tgt_labels[b * T + tt] == lf) first_hm = false;
        }
    }

    if (first_cell) atomicAdd(acc + 6, 1.0f);

    if (first_hm) {
        // focal correction: replace target-0 contribution with target-1 at this cell
        float x = heatmap[((b * NC + lf) * HH + gy) * WW + gx];
        float l1p = log1pf(expf(-fabsf(x)));
        float sp0 = fmaxf(x, 0.f) + l1p;      // softplus(x)  (ce for t=0)
        float sp1 = sp0 - x;                  // softplus(-x) (ce for t=1)
        float p = 1.f / (1.f + expf(-x));
        float qn = 1.f - p;
        atomicAdd(acc + 4, 0.25f * sp1 * qn * qn - 0.75f * sp0 * p * p);
    }

    if (last_cell) {
        // box_target last-write-wins at this cell; only pos cells contribute
        float s = 0.f;
        #pragma unroll
        for (int c = 0; c < 4; ++c)
            s += fabsf(box_map[((b * 4 + c) * HH + gy) * WW + gx] - bf[c]);
        atomicAdd(acc + 5, s);
    }

    // matched pair: src = pred_boxes[b, src_idx], tgt = boxes_n[b, tgt_idx]
    float mt[4];
    boxn_calc(tgt_boxes, b, ti, w_im, h_im, mt);
    const float* sb = pred_boxes + (b * Q + src_idx[b * T + t]) * 4;
    float s0 = sb[0], s1 = sb[1], s2 = sb[2], s3 = sb[3];

    float l1 = fabsf(s0 - mt[0]) + fabsf(s1 - mt[1]) + fabsf(s2 - mt[2]) + fabsf(s3 - mt[3]);

    // cxcywh -> xyxy
    float a0 = s0 - 0.5f * s2, a1 = s1 - 0.5f * s3, a2 = s0 + 0.5f * s2, a3 = s1 + 0.5f * s3;
    float b0 = mt[0] - 0.5f * mt[2], b1 = mt[1] - 0.5f * mt[3];
    float b2 = mt[0] + 0.5f * mt[2], b3 = mt[1] + 0.5f * mt[3];
    float area_a = (a2 - a0) * (a3 - a1), area_b = (b2 - b0) * (b3 - b1);
    float iw = fmaxf(fminf(a2, b2) - fmaxf(a0, b0), 0.f);
    float ih = fmaxf(fminf(a3, b3) - fmaxf(a1, b1), 0.f);
    float inter = iw * ih;
    float uni = area_a + area_b - inter;
    float iou = inter / uni;
    float cw_ = fmaxf(fmaxf(a2, b2) - fminf(a0, b0), 0.f);
    float ch_ = fmaxf(fmaxf(a3, b3) - fminf(a1, b1), 0.f);
    float area_c = cw_ * ch_;
    float giou = iou - (area_c - uni) / area_c;

    atomicAdd(acc + 2, l1);
    atomicAdd(acc + 3, 1.0f - giou);
}

// one wave (64 lanes) per row of 81 logits
__global__ void ce_kernel(const float* __restrict__ logits, const int* __restrict__ tc,
                          const float* __restrict__ empty_weight, float* acc) {
    int wid = (blockIdx.x * blockDim.x + threadIdx.x) >> 6;
    int lane = threadIdx.x & 63;
    if (wid >= B * Q) return;
    const float* row = logits + wid * CL;
    float x0 = row[lane];
    float x1 = (lane < CL - 64) ? row[lane + 64] : -INFINITY;
    float m = fmaxf(x0, x1);
    #pragma unroll
    for (int off = 32; off; off >>= 1) m = fmaxf(m, __shfl_xor(m, off));
    float s = expf(x0 - m) + ((lane < CL - 64) ? expf(x1 - m) : 0.f);
    #pragma unroll
    for (int off = 32; off; off >>= 1) s += __shfl_xor(s, off);
    if (lane == 0) {
        int tgt = tc[wid];
        float nll = (m + logf(s)) - row[tgt];
        float cw = empty_weight[tgt];
        atomicAdd(acc + 0, cw * nll);
        atomicAdd(acc + 1, cw);
    }
}

// focal-loss baseline assuming all targets are 0; corrections applied in pairs_kernel
__global__ void focal_kernel(const float* __restrict__ hm, float* acc) {
    const int N4 = B * NC * HH * WW / 4;
    int idx = blockIdx.x * blockDim.x + threadIdx.x;
    int stride = gridDim.x * blockDim.x;
    const float4* h4 = (const float4*)hm;
    float s = 0.f;
    for (int i = idx; i < N4; i += stride) {
        float4 v = h4[i];
        float xs[4] = {v.x, v.y, v.z, v.w};
        #pragma unroll
        for (int k = 0; k < 4; ++k) {
            float x = xs[k];
            float sp = fmaxf(x, 0.f) + log1pf(expf(-fabsf(x)));
            float p = 1.f / (1.f + expf(-x));
            s += sp * p * p;
        }
    }
    s *= 0.75f;
    #pragma unroll
    for (int off = 32; off; off >>= 1) s += __shfl_xor(s, off);
    __shared__ float wsum[4];
    int lane = threadIdx.x & 63, wv = threadIdx.x >> 6;
    if (lane == 0) wsum[wv] = s;
    __syncthreads();
    if (threadIdx.x == 0) {
        float tot = 0.f;
        for (int w = 0; w < (int)(blockDim.x >> 6); ++w) tot += wsum[w];
        atomicAdd(acc + 4, tot);
    }
}

__global__ void final_kernel(const float* acc, float* out) {
    float ce = acc[0] / acc[1];
    float bbox = acc[2] / (float)(B * T);
    float giou = acc[3] / (float)(B * T);
    float npos = fmaxf(acc[6], 1.0f);
    float aux = acc[4] / npos + 5.0f * (acc[5] / npos);
    out[0] = ce;
    out[1] = bbox;
    out[2] = giou;
    out[3] = aux;
    out[4] = ce + 5.f * bbox + 2.f * giou + aux;
}

extern "C" void kernel_launch(void* const* d_in, const int* in_sizes, int n_in,
                              void* d_out, int out_size, void* d_ws, size_t ws_size,
                              hipStream_t stream) {
    const float* pred_logits    = (const float*)d_in[0];
    const float* pred_boxes     = (const float*)d_in[1];
    const float* heatmap_logits = (const float*)d_in[2];
    const float* box_map        = (const float*)d_in[3];
    const float* tgt_boxes      = (const float*)d_in[4];
    const int*   tgt_labels     = (const int*)d_in[5];
    const float* tgt_sizes      = (const float*)d_in[6];
    const int*   src_idx        = (const int*)d_in[7];
    const int*   tgt_idx        = (const int*)d_in[8];
    const float* empty_weight   = (const float*)d_in[9];
    float* out = (float*)d_out;

    int* tc = (int*)d_ws;
    float* acc = (float*)((char*)d_ws + B * Q * sizeof(int));

    init_kernel<<<(B * Q + 255) / 256, 256, 0, stream>>>(tc, acc);
    pairs_kernel<<<(B * T + 255) / 256, 256, 0, stream>>>(
        pred_boxes, heatmap_logits, box_map, tgt_boxes, tgt_labels, tgt_sizes,
        src_idx, tgt_idx, tc, acc);
    ce_kernel<<<(B * Q * 64) / 256, 256, 0, stream>>>(pred_logits, tc, empty_weight, acc);
    focal_kernel<<<1024, 256, 0, stream>>>(heatmap_logits, acc);
    final_kernel<<<1, 1, 0, stream>>>(acc, out);
}

// Round 2
// 257.435 us; speedup vs baseline: 1.3960x; 1.3960x over previous
//
#include <hip/hip_runtime.h>
#include <math.h>

#define B 16
#define Q 300
#define T 50
#define NC 80
#define CL 81
#define HH 128
#define WW 128

#define NBLK_CE 120   // 480 waves, 10 rows each
#define NBLK_F  1024
#define NBLK_P  4     // ceil(800/256)

// ws layout (floats): pce[NBLK_CE] | pf[NBLK_F] | pp[NBLK_P*7]
// pp per block: 0 bbox, 1 giou, 2 focal_corr, 3 boxl, 4 npos, 5 ce_num_corr, 6 ce_den_corr

__device__ __forceinline__ void boxn_calc(const float* tb, float inv_w, float inv_h, float* o) {
    float x1 = tb[0] * inv_w, y1 = tb[1] * inv_h, x2 = tb[2] * inv_w, y2 = tb[3] * inv_h;
    o[0] = (x1 + x2) * 0.5f; o[1] = (y1 + y2) * 0.5f; o[2] = x2 - x1; o[3] = y2 - y1;
}

__global__ void pairs_kernel(const float* __restrict__ pred_logits,
                             const float* __restrict__ pred_boxes,
                             const float* __restrict__ heatmap,
                             const float* __restrict__ box_map,
                             const float* __restrict__ tgt_boxes,
                             const int* __restrict__ tgt_labels,
                             const float* __restrict__ tgt_sizes,
                             const int* __restrict__ src_idx,
                             const int* __restrict__ tgt_idx,
                             const float* __restrict__ ew,
                             float* __restrict__ pp) {
    int i = blockIdx.x * blockDim.x + threadIdx.x;
    float vals[7] = {0.f, 0.f, 0.f, 0.f, 0.f, 0.f, 0.f};

    if (i < B * T) {
        int b = i / T, t = i % T;
        float inv_h = 1.0f / tgt_sizes[b * 2 + 0];
        float inv_w = 1.0f / tgt_sizes[b * 2 + 1];

        float bf[4];
        boxn_calc(tgt_boxes + (b * T + t) * 4, inv_w, inv_h, bf);
        int gx = min(max((int)(bf[0] * WW), 0), WW - 1);
        int gy = min(max((int)(bf[1] * HH), 0), HH - 1);
        int lf = tgt_labels[b * T + t];

        // dedupe among targets in same batch mapping to same cell
        bool first_cell = true, first_hm = true, last_cell = true;
        for (int tt = 0; tt < T; ++tt) {
            if (tt == t) continue;
            float o[4];
            boxn_calc(tgt_boxes + (b * T + tt) * 4, inv_w, inv_h, o);
            int ox = min(max((int)(o[0] * WW), 0), WW - 1);
            int oy = min(max((int)(o[1] * HH), 0), HH - 1);
            if (ox == gx && oy == gy) {
                if (tt < t) first_cell = false;
                if (tt > t) last_cell = false;
                if (tt < t && tgt_labels[b * T + tt] == lf) first_hm = false;
            }
        }

        if (first_cell) vals[4] = 1.0f;

        if (first_hm) {
            // focal correction: replace target-0 term with target-1 at this cell
            float x = heatmap[((b * NC + lf) * HH + gy) * WW + gx];
            float l1p = log1pf(expf(-fabsf(x)));
            float sp0 = fmaxf(x, 0.f) + l1p;   // softplus(x)
            float sp1 = sp0 - x;               // softplus(-x)
            float p = 1.f / (1.f + expf(-x));
            float qn = 1.f - p;
            vals[2] = 0.25f * sp1 * qn * qn - 0.75f * sp0 * p * p;
        }

        if (last_cell) {
            float s = 0.f;
            #pragma unroll
            for (int c = 0; c < 4; ++c)
                s += fabsf(box_map[((b * 4 + c) * HH + gy) * WW + gx] - bf[c]);
            vals[3] = s;
        }

        // matched pair: src = pred_boxes[b, src_idx[b,t]], tgt = boxes_n[b, tgt_idx[b,t]]
        int ti = tgt_idx[b * T + t];
        int qi = src_idx[b * T + t];
        float mt[4];
        boxn_calc(tgt_boxes + (b * T + ti) * 4, inv_w, inv_h, mt);
        const float* sb = pred_boxes + (b * Q + qi) * 4;
        float s0 = sb[0], s1 = sb[1], s2 = sb[2], s3 = sb[3];

        vals[0] = fabsf(s0 - mt[0]) + fabsf(s1 - mt[1]) + fabsf(s2 - mt[2]) + fabsf(s3 - mt[3]);

        float a0 = s0 - 0.5f * s2, a1 = s1 - 0.5f * s3, a2 = s0 + 0.5f * s2, a3 = s1 + 0.5f * s3;
        float b0 = mt[0] - 0.5f * mt[2], b1 = mt[1] - 0.5f * mt[3];
        float b2 = mt[0] + 0.5f * mt[2], b3 = mt[1] + 0.5f * mt[3];
        float area_a = (a2 - a0) * (a3 - a1), area_b = (b2 - b0) * (b3 - b1);
        float iw = fmaxf(fminf(a2, b2) - fmaxf(a0, b0), 0.f);
        float ih = fmaxf(fminf(a3, b3) - fmaxf(a1, b1), 0.f);
        float inter = iw * ih;
        float uni = area_a + area_b - inter;
        float iou = inter / uni;
        float cw_ = fmaxf(fmaxf(a2, b2) - fminf(a0, b0), 0.f);
        float ch_ = fmaxf(fmaxf(a3, b3) - fminf(a1, b1), 0.f);
        float area_c = cw_ * ch_;
        vals[1] = 1.0f - (iou - (area_c - uni) / area_c);

        // CE correction for this matched row: replace NC-baseline with true label
        int lab = tgt_labels[b * T + ti];
        const float* row = pred_logits + (b * Q + qi) * CL;
        float m = -INFINITY;
        for (int c = 0; c < CL; ++c) m = fmaxf(m, row[c]);
        float se = 0.f;
        for (int c = 0; c < CL; ++c) se += expf(row[c] - m);
        float lse = m + logf(se);
        float wl = ew[lab], wn = ew[NC];
        vals[5] = wl * (lse - row[lab]) - wn * (lse - row[NC]);
        vals[6] = wl - wn;
    }

    // block reduce 7 values -> pp[blockIdx.x*7 + j]
    #pragma unroll
    for (int j = 0; j < 7; ++j)
        #pragma unroll
        for (int off = 32; off; off >>= 1) vals[j] += __shfl_xor(vals[j], off);
    __shared__ float lds[4][7];
    int lane = threadIdx.x & 63, wv = threadIdx.x >> 6;
    if (lane == 0)
        for (int j = 0; j < 7; ++j) lds[wv][j] = vals[j];
    __syncthreads();
    if (threadIdx.x == 0) {
        for (int j = 0; j < 7; ++j) {
            float s = lds[0][j] + lds[1][j] + lds[2][j] + lds[3][j];
            pp[blockIdx.x * 7 + j] = s;
        }
    }
}

// baseline CE: every row treated as unmatched (target = NC, weight = ew[NC])
__global__ void ce_kernel(const float* __restrict__ logits,
                          const float* __restrict__ ew,
                          float* __restrict__ pce) {
    int wave = (blockIdx.x * blockDim.x + threadIdx.x) >> 6;
    int lane = threadIdx.x & 63;
    const int NW = NBLK_CE * 4;
    float wNC = ew[NC];
    float num = 0.f;
    for (int r = wave; r < B * Q; r += NW) {
        const float* row = logits + r * CL;
        float x0 = row[lane];
        float x1 = (lane < CL - 64) ? row[lane + 64] : -INFINITY;
        float m = fmaxf(x0, x1);
        #pragma unroll
        for (int off = 32; off; off >>= 1) m = fmaxf(m, __shfl_xor(m, off));
        float s = expf(x0 - m) + ((lane < CL - 64) ? expf(x1 - m) : 0.f);
        #pragma unroll
        for (int off = 32; off; off >>= 1) s += __shfl_xor(s, off);
        float rNC = __shfl(x1, 16);            // row[80] lives in lane 16's x1
        if (lane == 0) num += wNC * ((m + logf(s)) - rNC);
    }
    __shared__ float lds[4];
    int wv = threadIdx.x >> 6;
    if (lane == 0) lds[wv] = num;
    __syncthreads();
    if (threadIdx.x == 0)
        pce[blockIdx.x] = lds[0] + lds[1] + lds[2] + lds[3];
}

// focal baseline assuming all targets are 0; corrections in pairs_kernel
__global__ void focal_kernel(const float* __restrict__ hm, float* __restrict__ pf) {
    const int N4 = B * NC * HH * WW / 4;
    int idx = blockIdx.x * blockDim.x + threadIdx.x;
    int stride = gridDim.x * blockDim.x;
    const float4* h4 = (const float4*)hm;
    float s = 0.f;
    for (int i = idx; i < N4; i += stride) {
        float4 v = h4[i];
        float xs[4] = {v.x, v.y, v.z, v.w};
        #pragma unroll
        for (int k = 0; k < 4; ++k) {
            float x = xs[k];
            float sp = fmaxf(x, 0.f) + log1pf(expf(-fabsf(x)));
            float p = 1.f / (1.f + expf(-x));
            s += sp * p * p;
        }
    }
    s *= 0.75f;
    #pragma unroll
    for (int off = 32; off; off >>= 1) s += __shfl_xor(s, off);
    __shared__ float wsum[4];
    int lane = threadIdx.x & 63, wv = threadIdx.x >> 6;
    if (lane == 0) wsum[wv] = s;
    __syncthreads();
    if (threadIdx.x == 0)
        pf[blockIdx.x] = wsum[0] + wsum[1] + wsum[2] + wsum[3];
}

__global__ void final_kernel(const float* __restrict__ pce,
                             const float* __restrict__ pf,
                             const float* __restrict__ pp,
                             const float* __restrict__ ew,
                             float* __restrict__ out) {
    __shared__ float lds[16];
    __shared__ float pps[NBLK_P * 7];
    int tid = threadIdx.x;
    float fsum = 0.f;
    for (int i = tid; i < NBLK_F; i += 256) fsum += pf[i];
    float cesum = 0.f;
    for (int i = tid; i < NBLK_CE; i += 256) cesum += pce[i];
    #pragma unroll
    for (int off = 32; off; off >>= 1) {
        fsum += __shfl_xor(fsum, off);
        cesum += __shfl_xor(cesum, off);
    }
    if (tid < NBLK_P * 7) pps[tid] = pp[tid];
    int lane = tid & 63, wv = tid >> 6;
    if (lane == 0) { lds[wv] = fsum; lds[8 + wv] = cesum; }
    __syncthreads();
    if (tid == 0) {
        float focal = lds[0] + lds[1] + lds[2] + lds[3];
        float cen   = lds[8] + lds[9] + lds[10] + lds[11];
        float s[7] = {0, 0, 0, 0, 0, 0, 0};
        for (int bk = 0; bk < NBLK_P; ++bk)
            for (int j = 0; j < 7; ++j) s[j] += pps[bk * 7 + j];
        float wNC = ew[NC];
        float ce = (cen + s[5]) / (wNC * (float)(B * Q) + s[6]);
        float bbox = s[0] / (float)(B * T);
        float giou = s[1] / (float)(B * T);
        float npos = fmaxf(s[4], 1.0f);
        float aux = (focal + s[2]) / npos + 5.0f * (s[3] / npos);
        out[0] = ce;
        out[1] = bbox;
        out[2] = giou;
        out[3] = aux;
        out[4] = ce + 5.f * bbox + 2.f * giou + aux;
    }
}

extern "C" void kernel_launch(void* const* d_in, const int* in_sizes, int n_in,
                              void* d_out, int out_size, void* d_ws, size_t ws_size,
                              hipStream_t stream) {
    const float* pred_logits    = (const float*)d_in[0];
    const float* pred_boxes     = (const float*)d_in[1];
    const float* heatmap_logits = (const float*)d_in[2];
    const float* box_map        = (const float*)d_in[3];
    const float* tgt_boxes      = (const float*)d_in[4];
    const int*   tgt_labels     = (const int*)d_in[5];
    const float* tgt_sizes      = (const float*)d_in[6];
    const int*   src_idx        = (const int*)d_in[7];
    const int*   tgt_idx        = (const int*)d_in[8];
    const float* empty_weight   = (const float*)d_in[9];
    float* out = (float*)d_out;

    float* pce = (float*)d_ws;
    float* pf  = pce + NBLK_CE;
    float* pp  = pf + NBLK_F;

    pairs_kernel<<<NBLK_P, 256, 0, stream>>>(
        pred_logits, pred_boxes, heatmap_logits, box_map, tgt_boxes, tgt_labels,
        tgt_sizes, src_idx, tgt_idx, empty_weight, pp);
    ce_kernel<<<NBLK_CE, 256, 0, stream>>>(pred_logits, empty_weight, pce);
    focal_kernel<<<NBLK_F, 256, 0, stream>>>(heatmap_logits, pf);
    final_kernel<<<1, 256, 0, stream>>>(pce, pf, pp, empty_weight, out);
}

// Round 3
// 147.144 us; speedup vs baseline: 2.4424x; 1.7495x over previous
//
#include <hip/hip_runtime.h>
#include <math.h>

#define B 16
#define Q 300
#define T 50
#define NC 80
#define CL 81
#define HH 128
#define WW 128

#define NBF 1024          // focal blocks
#define NBC 150           // ce blocks (600 waves, 8 rows each)
#define NBP 50            // pairs blocks (200 waves, 4 items each)
#define NBLK (NBF + NBC + NBP)

typedef unsigned long long ull;

__device__ __forceinline__ float frcp(float x) { return __builtin_amdgcn_rcpf(x); }

// ws: pf[NBF] | pce[NBC] | pp[NBP*7]
// pp: 0 bbox, 1 giou, 2 focal_corr, 3 boxl, 4 npos, 5 ce_num_corr, 6 ce_den_corr

__global__ __launch_bounds__(256) void main_kernel(
    const float* __restrict__ pred_logits,
    const float* __restrict__ pred_boxes,
    const float* __restrict__ heatmap,
    const float* __restrict__ box_map,
    const float* __restrict__ tgt_boxes,
    const int* __restrict__ tgt_labels,
    const float* __restrict__ tgt_sizes,
    const int* __restrict__ src_idx,
    const int* __restrict__ tgt_idx,
    const float* __restrict__ ew,
    float* __restrict__ pf, float* __restrict__ pce, float* __restrict__ pp) {

    __shared__ float smem[28];
    const int lane = threadIdx.x & 63;
    const int wv = threadIdx.x >> 6;

    if (blockIdx.x < NBF) {
        // ---------------- focal baseline (target = 0 everywhere) ----------------
        const int N4 = B * NC * HH * WW / 4;   // 5,242,880 -> 20 iters/thread exactly
        int idx = blockIdx.x * 256 + threadIdx.x;
        const int stride = NBF * 256;
        const float4* h4 = (const float4*)heatmap;
        float s = 0.f;
        for (int i = idx; i < N4; i += stride) {
            float4 v = h4[i];
            float xs[4] = {v.x, v.y, v.z, v.w};
            #pragma unroll
            for (int k = 0; k < 4; ++k) {
                float x = xs[k];
                float e = __expf(-fabsf(x));        // v_exp_f32
                float ope = 1.0f + e;
                float r = frcp(ope);                 // 1/(1+e) = sigmoid(|x|)
                float sp = fmaxf(x, 0.f) + __logf(ope);  // softplus(x); log arg in (1,2]
                float p = (x >= 0.f) ? r : e * r;    // sigmoid(x)
                s += sp * p * p;
            }
        }
        s *= 0.75f;
        #pragma unroll
        for (int off = 32; off; off >>= 1) s += __shfl_xor(s, off);
        if (lane == 0) smem[wv] = s;
        __syncthreads();
        if (threadIdx.x == 0)
            pf[blockIdx.x] = smem[0] + smem[1] + smem[2] + smem[3];

    } else if (blockIdx.x < NBF + NBC) {
        // ---------------- CE baseline (every row treated as unmatched) ----------------
        int wave = (blockIdx.x - NBF) * 4 + wv;
        const int NW = NBC * 4;
        float wNC = ew[NC];
        float num = 0.f;
        for (int r = wave; r < B * Q; r += NW) {
            const float* row = pred_logits + r * CL;
            float x0 = row[lane];
            float x1 = (lane < CL - 64) ? row[lane + 64] : -INFINITY;
            float m = fmaxf(x0, x1);
            #pragma unroll
            for (int off = 32; off; off >>= 1) m = fmaxf(m, __shfl_xor(m, off));
            float s = __expf(x0 - m) + ((lane < CL - 64) ? __expf(x1 - m) : 0.f);
            #pragma unroll
            for (int off = 32; off; off >>= 1) s += __shfl_xor(s, off);
            float rNC = __shfl(x1, 16);            // row[80] = lane16's x1
            if (lane == 0) num += wNC * ((m + __logf(s)) - rNC);
        }
        if (lane == 0) smem[wv] = num;
        __syncthreads();
        if (threadIdx.x == 0)
            pce[blockIdx.x - NBF] = smem[0] + smem[1] + smem[2] + smem[3];

    } else {
        // ---------------- pairs: one wave per matched item ----------------
        int pw = (blockIdx.x - NBF - NBC) * 4 + wv;
        const int NW = NBP * 4;
        float vals[7] = {0.f, 0.f, 0.f, 0.f, 0.f, 0.f, 0.f};  // lane0-held sums

        for (int i = pw; i < B * T; i += NW) {
            int b = i / T, t = i % T;
            float inv_h = frcp(tgt_sizes[b * 2 + 0]);
            float inv_w = frcp(tgt_sizes[b * 2 + 1]);

            // lane `l` computes normalized box + cell of target (b, l)
            int lidx = b * T + ((lane < T) ? lane : 0);
            float4 tb = ((const float4*)tgt_boxes)[lidx];
            float ocx = (tb.x + tb.z) * 0.5f * inv_w;
            float ocy = (tb.y + tb.w) * 0.5f * inv_h;
            float ow = (tb.z - tb.x) * inv_w;
            float oh = (tb.w - tb.y) * inv_h;
            int ox = min(max((int)(ocx * WW), 0), WW - 1);
            int oy = min(max((int)(ocy * HH), 0), HH - 1);
            int labl = (lane < T) ? tgt_labels[b * T + lane] : -1;

            int gx = __shfl(ox, t), gy = __shfl(oy, t), lf = __shfl(labl, t);
            float bf0 = __shfl(ocx, t), bf1 = __shfl(ocy, t);
            float bf2 = __shfl(ow, t), bf3 = __shfl(oh, t);

            ull same = __ballot(lane < T && ox == gx && oy == gy);
            ull same_lab = __ballot(lane < T && ox == gx && oy == gy && labl == lf);
            ull below = (1ull << t) - 1ull;
            ull above = ~((1ull << (t + 1)) - 1ull);
            bool first_cell = (same & below) == 0;
            bool last_cell = (same & above) == 0;
            bool first_hm = (same_lab & below) == 0;

            int ti = tgt_idx[b * T + t];
            int qi = src_idx[b * T + t];
            float mt0 = __shfl(ocx, ti), mt1 = __shfl(ocy, ti);
            float mt2 = __shfl(ow, ti), mt3 = __shfl(oh, ti);
            int lab = __shfl(labl, ti);

            // CE correction: lane-parallel logsumexp over row (b*Q+qi)
            const float* row = pred_logits + (b * Q + qi) * CL;
            float x0 = row[lane];
            float x1 = (lane < CL - 64) ? row[lane + 64] : -INFINITY;
            float m = fmaxf(x0, x1);
            #pragma unroll
            for (int off = 32; off; off >>= 1) m = fmaxf(m, __shfl_xor(m, off));
            float se = __expf(x0 - m) + ((lane < CL - 64) ? __expf(x1 - m) : 0.f);
            #pragma unroll
            for (int off = 32; off; off >>= 1) se += __shfl_xor(se, off);
            float lse = m + __logf(se);
            float rlab = (lab < 64) ? __shfl(x0, lab) : __shfl(x1, lab - 64);
            float rNC = __shfl(x1, 16);

            if (lane == 0) {
                float wl = ew[lab], wn = ew[NC];
                vals[5] += wl * (lse - rlab) - wn * (lse - rNC);
                vals[6] += wl - wn;

                if (first_cell) vals[4] += 1.0f;

                if (first_hm) {
                    float x = heatmap[((b * NC + lf) * HH + gy) * WW + gx];
                    float e = __expf(-fabsf(x));
                    float ope = 1.0f + e;
                    float r = frcp(ope);
                    float l1p = __logf(ope);
                    float sp0 = fmaxf(x, 0.f) + l1p;   // softplus(x)
                    float sp1 = sp0 - x;               // softplus(-x)
                    float p = (x >= 0.f) ? r : e * r;
                    float qn = 1.f - p;
                    vals[2] += 0.25f * sp1 * qn * qn - 0.75f * sp0 * p * p;
                }

                if (last_cell) {
                    float bfc[4] = {bf0, bf1, bf2, bf3};
                    float sbl = 0.f;
                    #pragma unroll
                    for (int c = 0; c < 4; ++c)
                        sbl += fabsf(box_map[((b * 4 + c) * HH + gy) * WW + gx] - bfc[c]);
                    vals[3] += sbl;
                }

                // pair L1 + GIoU
                float4 sb = ((const float4*)pred_boxes)[b * Q + qi];
                float s0 = sb.x, s1 = sb.y, s2 = sb.z, s3 = sb.w;
                vals[0] += fabsf(s0 - mt0) + fabsf(s1 - mt1) + fabsf(s2 - mt2) + fabsf(s3 - mt3);

                float a0 = s0 - 0.5f * s2, a1 = s1 - 0.5f * s3;
                float a2 = s0 + 0.5f * s2, a3 = s1 + 0.5f * s3;
                float b0 = mt0 - 0.5f * mt2, b1 = mt1 - 0.5f * mt3;
                float b2 = mt0 + 0.5f * mt2, b3 = mt1 + 0.5f * mt3;
                float area_a = (a2 - a0) * (a3 - a1), area_b = (b2 - b0) * (b3 - b1);
                float iw = fmaxf(fminf(a2, b2) - fmaxf(a0, b0), 0.f);
                float ih = fmaxf(fminf(a3, b3) - fmaxf(a1, b1), 0.f);
                float inter = iw * ih;
                float uni = area_a + area_b - inter;
                float iou = inter / uni;
                float cw_ = fmaxf(fmaxf(a2, b2) - fminf(a0, b0), 0.f);
                float ch_ = fmaxf(fmaxf(a3, b3) - fminf(a1, b1), 0.f);
                float area_c = cw_ * ch_;
                vals[1] += 1.0f - (iou - (area_c - uni) / area_c);
            }
        }

        if (lane == 0)
            for (int j = 0; j < 7; ++j) smem[wv * 7 + j] = vals[j];
        __syncthreads();
        if (threadIdx.x == 0) {
            int blockrel = blockIdx.x - NBF - NBC;
            for (int j = 0; j < 7; ++j)
                pp[blockrel * 7 + j] = smem[j] + smem[7 + j] + smem[14 + j] + smem[21 + j];
        }
    }
}

__global__ __launch_bounds__(256) void final_kernel(
    const float* __restrict__ pf, const float* __restrict__ pce,
    const float* __restrict__ pp, const float* __restrict__ ew,
    float* __restrict__ out) {
    __shared__ float lds[16];
    __shared__ float s7[7];
    int tid = threadIdx.x;
    if (tid < 7) s7[tid] = 0.f;
    __syncthreads();
    float fsum = 0.f;
    for (int i = tid; i < NBF; i += 256) fsum += pf[i];
    float cesum = 0.f;
    for (int i = tid; i < NBC; i += 256) cesum += pce[i];
    #pragma unroll
    for (int off = 32; off; off >>= 1) {
        fsum += __shfl_xor(fsum, off);
        cesum += __shfl_xor(cesum, off);
    }
    for (int i = tid; i < NBP * 7; i += 256) atomicAdd(&s7[i % 7], pp[i]);
    int lane = tid & 63, wv = tid >> 6;
    if (lane == 0) { lds[wv] = fsum; lds[8 + wv] = cesum; }
    __syncthreads();
    if (tid == 0) {
        float focal = lds[0] + lds[1] + lds[2] + lds[3];
        float cen = lds[8] + lds[9] + lds[10] + lds[11];
        float wNC = ew[NC];
        float ce = (cen + s7[5]) / (wNC * (float)(B * Q) + s7[6]);
        float bbox = s7[0] / (float)(B * T);
        float giou = s7[1] / (float)(B * T);
        float npos = fmaxf(s7[4], 1.0f);
        float aux = (focal + s7[2]) / npos + 5.0f * (s7[3] / npos);
        out[0] = ce;
        out[1] = bbox;
        out[2] = giou;
        out[3] = aux;
        out[4] = ce + 5.f * bbox + 2.f * giou + aux;
    }
}

extern "C" void kernel_launch(void* const* d_in, const int* in_sizes, int n_in,
                              void* d_out, int out_size, void* d_ws, size_t ws_size,
                              hipStream_t stream) {
    const float* pred_logits    = (const float*)d_in[0];
    const float* pred_boxes     = (const float*)d_in[1];
    const float* heatmap_logits = (const float*)d_in[2];
    const float* box_map        = (const float*)d_in[3];
    const float* tgt_boxes      = (const float*)d_in[4];
    const int*   tgt_labels     = (const int*)d_in[5];
    const float* tgt_sizes      = (const float*)d_in[6];
    const int*   src_idx        = (const int*)d_in[7];
    const int*   tgt_idx        = (const int*)d_in[8];
    const float* empty_weight   = (const float*)d_in[9];
    float* out = (float*)d_out;

    float* pf  = (float*)d_ws;
    float* pce = pf + NBF;
    float* pp  = pce + NBC;

    main_kernel<<<NBLK, 256, 0, stream>>>(
        pred_logits, pred_boxes, heatmap_logits, box_map, tgt_boxes, tgt_labels,
        tgt_sizes, src_idx, tgt_idx, empty_weight, pf, pce, pp);
    final_kernel<<<1, 256, 0, stream>>>(pf, pce, pp, empty_weight, out);
}